// Round 10
// baseline (5984.727 us; speedup 1.0000x reference)
//
#include <hip/hip_runtime.h>

// NODE scan: 32 groups x 8 blocks; group = 16 batch rows; block j owns a
// 64-col slice of W1/W2, 64-ROW slice of W3 (partial-v reduce), 8 cols of Wr.
// R10 = R8 base (sc1 flags ONLY — sc0 flags regressed twice in A/B) +
// (1) per-wave sub-flags: each wave drains its own stores and releases its
//     own flag; consumer polls 32 sub-flags; no block barrier in release.
// (2) pipelined 2-deep flag poll (counted vmcnt(1), value tied thru asm).
// (3) out/lat/x HBM traffic deferred to gap1 where the vp poll's first
//     counted wait absorbs the store-ack concurrently with flag flight.
// Data plane: sc0 (XCD-L2) iff startup probe proves coherence, else sc0 sc1.

#define TT 1000
#define II 16
#define LL 128
#define HH 512
#define OO 64
#define BB 512

typedef _Float16 f16;
typedef _Float16 f16x8 __attribute__((ext_vector_type(8)));
typedef _Float16 f16x4 __attribute__((ext_vector_type(4)));
typedef float    f32x4 __attribute__((ext_vector_type(4)));
typedef unsigned u32x2 __attribute__((ext_vector_type(2)));
typedef unsigned u32x4 __attribute__((ext_vector_type(4)));

#define MFMA16(a, b, c) __builtin_amdgcn_mfma_f32_16x16x32_f16((a), (b), (c), 0, 0, 0)

// f16 row strides: row byte-size MUST be a multiple of 128 (XOR block size).
#define ZS2  256   // 512B: z 0..159 | vpT 64..191 | a2 192..255
#define W1S  192   // 384B = 3*128
#define W2S  512   // 1024B
#define W3S  64    // 128B
#define WRS  128   // 256B

// swizzled address: row-base + (2*colf16 ^ ((row&7)<<4))
#define SWB(rowptr, row, colf16) \
  ((void*)((char*)(rowptr) + ((2 * (colf16)) ^ (((row) & 7) << 4))))

struct Lds {
  f16 w1t[64][W1S];
  f16 w2t[64][W2S];
  f16 w3t[128][W3S];
  f16 wrt[16][WRS];
  f16 act[16][ZS2];
  float b1c[64], b2c[64], b3c[128], brc[16];
  int xtmp[8];
};

// ---- always-coherent (L3) primitives ----
__device__ __forceinline__ void st_sc1_u32(void* p, unsigned v) {
  asm volatile("global_store_dword %0, %1, off sc0 sc1" :: "v"(p), "v"(v) : "memory");
}
__device__ __forceinline__ unsigned ld_sc1_u32(const void* p) {
  unsigned r;
  asm volatile("global_load_dword %0, %1, off sc0 sc1\n\ts_waitcnt vmcnt(0)"
               : "=v"(r) : "v"(p) : "memory");
  return r;
}
// ---- XCD-L2 primitives (used only where probe proved coherence) ----
__device__ __forceinline__ void st_sc0_u32(void* p, unsigned v) {
  asm volatile("global_store_dword %0, %1, off sc0" :: "v"(p), "v"(v) : "memory");
}
__device__ __forceinline__ unsigned ld_sc0_u32(const void* p) {
  unsigned r;
  asm volatile("global_load_dword %0, %1, off sc0\n\ts_waitcnt vmcnt(0)"
               : "=v"(r) : "v"(p) : "memory");
  return r;
}
template <bool FAST> __device__ __forceinline__ void st_c_u2(void* p, u32x2 v) {
  if constexpr (FAST) asm volatile("global_store_dwordx2 %0, %1, off sc0"     :: "v"(p), "v"(v) : "memory");
  else                asm volatile("global_store_dwordx2 %0, %1, off sc0 sc1" :: "v"(p), "v"(v) : "memory");
}
template <bool FAST> __device__ __forceinline__ void st_c_u4(void* p, u32x4 v) {
  if constexpr (FAST) asm volatile("global_store_dwordx4 %0, %1, off sc0"     :: "v"(p), "v"(v) : "memory");
  else                asm volatile("global_store_dwordx4 %0, %1, off sc0 sc1" :: "v"(p), "v"(v) : "memory");
}
template <bool FAST> __device__ __forceinline__ u32x4 ld_c_u4(const void* p) {
  u32x4 r;
  if constexpr (FAST) asm volatile("global_load_dwordx4 %0, %1, off sc0"     : "=v"(r) : "v"(p) : "memory");
  else                asm volatile("global_load_dwordx4 %0, %1, off sc0 sc1" : "=v"(r) : "v"(p) : "memory");
  return r;
}
__device__ __forceinline__ void vm_drain() {
  asm volatile("s_waitcnt vmcnt(0)" ::: "memory");
  __builtin_amdgcn_sched_barrier(0);   // rule #18
}

// ---- pipelined 2-deep flag poll (flags always sc1) ----
__device__ __forceinline__ unsigned ld_flag_nw(const unsigned* p) {
  unsigned r;
  asm volatile("global_load_dword %0, %1, off sc0 sc1" : "=v"(r) : "v"(p));
  return r;
}
// counted wait; ties v through the asm so the compare can't hoist (rule #18)
__device__ __forceinline__ unsigned wait_vm1_pass(unsigned v) {
  asm volatile("s_waitcnt vmcnt(1)" : "+v"(v) :: "memory");
  __builtin_amdgcn_sched_barrier(0);
  return v;
}
__device__ __forceinline__ void poll2(const unsigned* p, unsigned tgt) {
  unsigned a = ld_flag_nw(p);
  unsigned b = ld_flag_nw(p);
  for (;;) {
    a = wait_vm1_pass(a);     // all older vm ops (incl. gap stores) drained
    if (a >= tgt) break;
    a = b;
    b = ld_flag_nw(p);
  }
  vm_drain();                 // retire trailing poll load
}

// flag layout per group (1024 u32): a1 sub-flag (j,w) at [(j*4+w)*16],
// vp sub-flag at [512 + (j*4+w)*16]  (64B spread per flag)
template <bool FAST>
__device__ void run_loop(Lds& s, const float* __restrict__ x,
                         float* __restrict__ out, float* __restrict__ lat,
                         unsigned* __restrict__ fl,
                         f16* __restrict__ a1buf, f16* __restrict__ vpbuf,
                         int j, int g, int tid, int w, int lr, int lk) {
  const int r    = tid >> 4;
  const int cg   = tid & 15;
  const int lane = tid & 63;
  const size_t xoff = (size_t)(g * 16 + r) * TT * II + cg;
  float xr = 0.f;
  float hreg[8] = {0.f, 0.f, 0.f, 0.f, 0.f, 0.f, 0.f, 0.f};

  for (int t = 0; t < TT; ++t) {
    const int par = t & 1;
    f16* const a1b = a1buf + (size_t)(g * 2 + par) * (16 * 512);
    f16* const vpb = vpbuf + (size_t)(g * 2 + par) * (8 * 16 * 128);

    // -------- phase A: a1_chunk = relu(z @ W1_slice + b1) ------------------
    {
      const int n = w * 16 + lr;
      f32x4 c = {0.f, 0.f, 0.f, 0.f};
#pragma unroll
      for (int kt = 0; kt < 5; ++kt) {
        f16x8 wf = *(const f16x8*)SWB(&s.w1t[n][0], n, kt * 32 + lk * 8);
        f16x8 zf = *(const f16x8*)SWB(&s.act[lr][0], lr, kt * 32 + lk * 8);
        c = MFMA16(wf, zf, c);
      }
      f16x4 o;
#pragma unroll
      for (int e = 0; e < 4; ++e) {
        float vv = c[e] + s.b1c[w * 16 + lk * 4 + e];
        vv = vv > 0.f ? vv : 0.f;
        o[e] = (f16)vv;
      }
      st_c_u2<FAST>(a1b + (size_t)lr * 512 + 64 * j + w * 16 + lk * 4,
                    __builtin_bit_cast(u32x2, o));
    }
    // per-wave release: drain own store, lane0 posts sub-flag (no barrier!)
    vm_drain();
    if (lane == 0) st_sc1_u32(fl + (j * 4 + w) * 16, (unsigned)(t + 1));

    // -------- gap0: out_{t-1} MFMA into REGISTERS only (w0) ----------------
    f32x4 oreg = {0.f, 0.f, 0.f, 0.f};
    if (t > 0 && w == 0) {
      f32x4 c = {0.f, 0.f, 0.f, 0.f};
#pragma unroll
      for (int kt = 0; kt < 4; ++kt) {
        f16x8 a = *(const f16x8*)SWB(&s.act[lr][0], lr, kt * 32 + lk * 8);
        f16x8 b = *(const f16x8*)SWB(&s.wrt[lr][0], lr, kt * 32 + lk * 8);
        c = MFMA16(a, b, c);
      }
      oreg = c;
    }

    // -------- WAIT a1 (32 sub-flags, pipelined poll; wave queue clean) -----
    if (lane < 32) poll2(fl + lane * 16, (unsigned)(t + 1));

    // -------- phase B: a2_chunk = relu(a1 @ W2_slice + b2) -> act[192..] ---
    {
      const int bn = w * 16 + lr;
      u32x4 araw[16];
#pragma unroll
      for (int kt = 0; kt < 16; ++kt)
        araw[kt] = ld_c_u4<FAST>(a1b + (size_t)lr * 512 + kt * 32 + lk * 8);
      vm_drain();
      f32x4 c0 = {0.f, 0.f, 0.f, 0.f}, c1 = {0.f, 0.f, 0.f, 0.f};
#pragma unroll
      for (int kt = 0; kt < 16; kt += 2) {
        f16x8 b0 = *(const f16x8*)SWB(&s.w2t[bn][0], bn, kt * 32 + lk * 8);
        c0 = MFMA16(__builtin_bit_cast(f16x8, araw[kt]), b0, c0);
        f16x8 b1_ = *(const f16x8*)SWB(&s.w2t[bn][0], bn, (kt + 1) * 32 + lk * 8);
        c1 = MFMA16(__builtin_bit_cast(f16x8, araw[kt + 1]), b1_, c1);
      }
#pragma unroll
      for (int e = 0; e < 4; ++e) {
        float vv = c0[e] + c1[e] + s.b2c[bn];
        vv = vv > 0.f ? vv : 0.f;
        *(f16*)SWB(&s.act[lk * 4 + e][0], lk * 4 + e, 192 + bn) = (f16)vv;
      }
    }
    __syncthreads();   // a2 visible to all waves

    // -------- phase C: vp = a2 @ W3_rows; wave-local vpT + store -----------
    {
      const int nt0 = 2 * w, nt1 = 2 * w + 1;
      f32x4 c0 = {0.f, 0.f, 0.f, 0.f}, c1 = {0.f, 0.f, 0.f, 0.f};
#pragma unroll
      for (int kt = 0; kt < 2; ++kt) {
        f16x8 a = *(const f16x8*)SWB(&s.act[lr][0], lr, 192 + kt * 32 + lk * 8);
        f16x8 b0 = *(const f16x8*)SWB(&s.w3t[nt0 * 16 + lr][0], nt0 * 16 + lr, kt * 32 + lk * 8);
        c0 = MFMA16(a, b0, c0);
        f16x8 b1_ = *(const f16x8*)SWB(&s.w3t[nt1 * 16 + lr][0], nt1 * 16 + lr, kt * 32 + lk * 8);
        c1 = MFMA16(a, b1_, c1);
      }
#pragma unroll
      for (int e = 0; e < 4; ++e) {           // vpT cols 64+32w..64+32w+31
        *(f16*)SWB(&s.act[lk * 4 + e][0], lk * 4 + e, 64 + nt0 * 16 + lr) = (f16)c0[e];
        *(f16*)SWB(&s.act[lk * 4 + e][0], lk * 4 + e, 64 + nt1 * 16 + lr) = (f16)c1[e];
      }
      // wave stores ONLY the cols it wrote (same-wave LDS dep, no barrier)
      const int vr = lane >> 2, vc = (lane & 3) * 8;
      u32x4 vv = *(const u32x4*)SWB(&s.act[vr][0], vr, 64 + 32 * w + vc);
      st_c_u4<FAST>(vpb + (size_t)j * 2048 + (size_t)vr * 128 + 32 * w + vc, vv);
    }
    // per-wave release of vp sub-flag
    vm_drain();
    if (lane == 0) st_sc1_u32(fl + 512 + (j * 4 + w) * 16, (unsigned)(t + 1));

    // -------- gap1: deferred HBM traffic (absorbed by vp poll's 1st wait) --
    if (t > 0) {
      if ((cg >> 1) == j) {   // lat slice for t-1 from hreg
        float* dst = lat + ((size_t)(g * 16 + r) * TT + (t - 1)) * LL + cg * 8;
        *(f32x4*)dst = *(f32x4*)&hreg[0];
        *(f32x4*)(dst + 4) = *(f32x4*)&hreg[4];
      }
      if (w == 0 && lr < 8) {  // out slice for t-1 from oreg
#pragma unroll
        for (int e = 0; e < 4; ++e)
          out[((size_t)(g * 16 + lk * 4 + e) * TT + (t - 1)) * OO + 8 * j + lr] =
              oreg[e] + s.brc[lr];
      }
    }
    xr = (t + 1 < TT) ? x[xoff + (size_t)(t + 1) * II] : 0.f;

    // -------- WAIT vp (32 sub-flags, pipelined poll) -----------------------
    if (lane < 32) poll2(fl + 512 + lane * 16, (unsigned)(t + 1));

    // -------- phase D: v = sum_j vp_j + b3; h += 0.1v; rebuild z -----------
    {
      const f16* vb = vpb + (size_t)r * 128 + cg * 8;
      u32x4 p[8];
#pragma unroll
      for (int m = 0; m < 8; ++m) p[m] = ld_c_u4<FAST>(vb + (size_t)m * 2048);
      vm_drain();
      float sum[8] = {0.f, 0.f, 0.f, 0.f, 0.f, 0.f, 0.f, 0.f};
#pragma unroll
      for (int m = 0; m < 8; ++m) {
        f16x8 ph = __builtin_bit_cast(f16x8, p[m]);
#pragma unroll
        for (int e = 0; e < 8; ++e) sum[e] += (float)ph[e];
      }
      f16x8 zf;
#pragma unroll
      for (int e = 0; e < 8; ++e) {
        hreg[e] += 0.1f * (sum[e] + s.b3c[cg * 8 + e]);
        zf[e] = (f16)hreg[e];
      }
      *(f16x8*)SWB(&s.act[r][0], r, cg * 8) = zf;
      *(f16*)SWB(&s.act[r][0], r, 128 + cg) = (f16)xr;
      *(f16*)SWB(&s.act[r][0], r, 144 + cg) = (f16)0.f;   // re-zero K pad
    }
    __syncthreads();   // z ready for next A
  }

  // -------- epilogue: lat + out for t = TT-1 --------------------------------
  if ((cg >> 1) == j) {
    float* dst = lat + ((size_t)(g * 16 + r) * TT + (TT - 1)) * LL + cg * 8;
    *(f32x4*)dst = *(f32x4*)&hreg[0];
    *(f32x4*)(dst + 4) = *(f32x4*)&hreg[4];
  }
  if (w == 0) {
    f32x4 c = {0.f, 0.f, 0.f, 0.f};
#pragma unroll
    for (int kt = 0; kt < 4; ++kt) {
      f16x8 a = *(const f16x8*)SWB(&s.act[lr][0], lr, kt * 32 + lk * 8);
      f16x8 b = *(const f16x8*)SWB(&s.wrt[lr][0], lr, kt * 32 + lk * 8);
      c = MFMA16(a, b, c);
    }
    if (lr < 8) {
#pragma unroll
      for (int e = 0; e < 4; ++e)
        out[((size_t)(g * 16 + lk * 4 + e) * TT + (TT - 1)) * OO + 8 * j + lr] =
            c[e] + s.brc[lr];
    }
  }
}

__launch_bounds__(256, 1)
__global__ void node_scan_kernel(
    const float* __restrict__ x,
    const float* __restrict__ W1, const float* __restrict__ b1,
    const float* __restrict__ W2, const float* __restrict__ b2,
    const float* __restrict__ W3, const float* __restrict__ b3,
    const float* __restrict__ Wr, const float* __restrict__ br,
    float* __restrict__ out,
    unsigned* __restrict__ flags, unsigned* __restrict__ xccbuf,
    unsigned* __restrict__ pflag, unsigned* __restrict__ pack,
    unsigned* __restrict__ verd,  unsigned* __restrict__ pdata,
    f16* __restrict__ a1buf, f16* __restrict__ vpbuf)
{
  __shared__ Lds s;
  const int tid  = threadIdx.x;
  const int bid  = blockIdx.x;
  const int q    = bid >> 3;
  const int j    = q & 7;
  const int g    = (bid & 7) + 8 * (q >> 3);    // group 0..31 (co-XCD heuristic)
  const int lane = tid & 63;
  const int w    = tid >> 6;
  const int lr   = lane & 15;
  const int lk   = lane >> 4;

  float* lat = out + (size_t)BB * TT * OO;

  // ---------------- prologue: weights -> LDS (transposed, f16, swizzled) ---
  { int n = tid & 63, ks = tid >> 6;
    for (int k = ks; k < 144; k += 4)
      *(f16*)SWB(&s.w1t[n][0], n, k) = (f16)W1[(size_t)k * HH + 64 * j + n];
    for (int k = 144 + ks; k < 160; k += 4)
      *(f16*)SWB(&s.w1t[n][0], n, k) = (f16)0.f;
    for (int k = ks; k < HH; k += 4)
      *(f16*)SWB(&s.w2t[n][0], n, k) = (f16)W2[(size_t)k * HH + 64 * j + n];
  }
  for (int idx = tid; idx < 128 * 64; idx += 256) {
    int kl = idx >> 7, n = idx & 127;
    *(f16*)SWB(&s.w3t[n][0], n, kl) = (f16)W3[(size_t)(64 * j + kl) * LL + n];
  }
  { int n = tid & 15, ks = tid >> 4;
    for (int k = ks; k < LL; k += 16)
      *(f16*)SWB(&s.wrt[n][0], n, k) =
          (n < 8) ? (f16)Wr[(size_t)k * OO + 8 * j + n] : (f16)0.f;
  }
  if (tid < 64)       { s.b1c[tid] = b1[64 * j + tid]; s.b2c[tid] = b2[64 * j + tid]; }
  else if (tid < 192) { s.b3c[tid - 64] = b3[tid - 64]; }
  else if (tid < 208) { int n = tid - 192; s.brc[n] = (n < 8) ? br[8 * j + n] : 0.f; }
  for (int i = tid; i < 16 * ZS2; i += 256) ((f16*)s.act)[i] = (f16)0.f;

  // ---------------- XCD-placement exchange (sc1, proven live) --------------
  int xcc;
  asm volatile("s_getreg_b32 %0, hwreg(HW_REG_XCC_ID)" : "=s"(xcc));
  xcc &= 15;
  if (tid == 0) { st_sc1_u32(xccbuf + g * 8 + j, 0x100u | (unsigned)xcc); vm_drain(); }
  if (tid < 8) {
    unsigned v;
    const unsigned* p = xccbuf + g * 8 + tid;
    do { v = ld_sc1_u32(p); } while (!(v & 0x100u));
    s.xtmp[tid] = (int)(v & 0xffu);
  }
  __syncthreads();
  bool fast = true;
  for (int k2 = 1; k2 < 8; ++k2) fast = fast && (s.xtmp[k2] == s.xtmp[0]);

  // ---------------- sc0 coherence probe (3 rounds, no sc0 spin) ------------
  unsigned okbit = 1u;
  if (fast) {
    unsigned* pd = pdata + g * 8;
    unsigned* pf = pflag + g * 8;
    unsigned* pa = pack  + g * 8;
    const unsigned X = 0x51A00000u | ((unsigned)j << 4);
#pragma unroll 1
    for (int rnd = 0; rnd < 3; ++rnd) {
      unsigned val = (rnd == 1) ? (X | 1u) : X;   // rnd2 restores X
      if (tid == 0) {
        st_sc0_u32(pd + j, val);
        vm_drain();
        st_sc1_u32(pf + j, (unsigned)(rnd + 1));
        vm_drain();
      }
      if (tid < 8) {
        while (ld_sc1_u32(pf + tid) < (unsigned)(rnd + 1)) { }
        if (rnd < 2) {
          unsigned exp = 0x51A00000u | ((unsigned)tid << 4) | (rnd == 1 ? 1u : 0u);
          if (ld_sc0_u32(pd + tid) != exp) okbit = 0u;
        }
      }
      __syncthreads();
      if (tid == 0) { st_sc1_u32(pa + j, (unsigned)(rnd + 1)); vm_drain(); }
      if (tid < 8) { while (ld_sc1_u32(pa + tid) < (unsigned)(rnd + 1)) { } }
      __syncthreads();
    }
    if (tid < 8) s.xtmp[tid] = (int)okbit;
    __syncthreads();
    for (int k2 = 0; k2 < 8; ++k2) fast = fast && (s.xtmp[k2] != 0);
  }
  // ---------------- verdict exchange: group-uniform FAST/SLOW --------------
  if (tid == 0) { st_sc1_u32(verd + g * 8 + j, 0x100u | (fast ? 1u : 0u)); vm_drain(); }
  if (tid < 8) {
    unsigned v;
    const unsigned* p = verd + g * 8 + tid;
    do { v = ld_sc1_u32(p); } while (!(v & 0x100u));
    s.xtmp[tid] = (int)(v & 1u);
  }
  __syncthreads();
  bool FASTRUN = true;
  for (int k2 = 0; k2 < 8; ++k2) FASTRUN = FASTRUN && (s.xtmp[k2] != 0);

  // z_0 = [0 | x_0 | 0]
  { const int rr = tid >> 4, cc = tid & 15;
    *(f16*)SWB(&s.act[rr][0], rr, 128 + cc) =
        (f16)x[(size_t)(g * 16 + rr) * TT * II + cc]; }
  __syncthreads();

  unsigned* const fl = flags + g * 1024;
  if (FASTRUN) run_loop<true >(s, x, out, lat, fl, a1buf, vpbuf, j, g, tid, w, lr, lk);
  else         run_loop<false>(s, x, out, lat, fl, a1buf, vpbuf, j, g, tid, w, lr, lk);
}

extern "C" void kernel_launch(void* const* d_in, const int* in_sizes, int n_in,
                              void* d_out, int out_size, void* d_ws, size_t ws_size,
                              hipStream_t stream) {
  const float* x  = (const float*)d_in[0];
  const float* W1 = (const float*)d_in[1];
  const float* b1 = (const float*)d_in[2];
  const float* W2 = (const float*)d_in[3];
  const float* b2 = (const float*)d_in[4];
  const float* W3 = (const float*)d_in[5];
  const float* b3 = (const float*)d_in[6];
  const float* Wr = (const float*)d_in[7];
  const float* br = (const float*)d_in[8];
  float* out = (float*)d_out;

  // ws: [0,128K) flags (32 groups x 1024 u32: 32 a1 + 32 vp sub-flags,
  // 64B-spread) | [128K) xcc | [129K) pflag | [130K) pack | [131K) verd
  // (memset [0,132K)) | [132K,133K) pdata (sc0 probe, NOT memset) |
  // [192K) 1MB a1buf | [192K+1M) 2MB vpbuf
  unsigned* flags  = (unsigned*)d_ws;
  unsigned* xccbuf = (unsigned*)((char*)d_ws + 131072);
  unsigned* pflag  = (unsigned*)((char*)d_ws + 132096);
  unsigned* pack   = (unsigned*)((char*)d_ws + 133120);
  unsigned* verd   = (unsigned*)((char*)d_ws + 134144);
  unsigned* pdata  = (unsigned*)((char*)d_ws + 135168);
  f16* a1buf = (f16*)((char*)d_ws + 196608);
  f16* vpbuf = (f16*)((char*)d_ws + 196608 + (1 << 20));

  hipMemsetAsync(d_ws, 0, 135168, stream);  // flags + probe ctrl (not pdata)
  node_scan_kernel<<<256, 256, 0, stream>>>(x, W1, b1, W2, b2, W3, b3, Wr, br,
                                            out, flags, xccbuf, pflag, pack,
                                            verd, pdata, a1buf, vpbuf);
}

// Round 11
// 3948.218 us; speedup vs baseline: 1.5158x; 1.5158x over previous
//
#include <hip/hip_runtime.h>

// NODE scan R11: ONE sync/step. 64 groups x 4 blocks; group = 8 batch rows.
// Block j: W1 cols 128j..128j+128 (LDS), W2 rows 128j..128j+128 (REGISTERS),
// full W3 (REGISTERS), Wr cols 16j..16j+16 (registers). Per step:
// A: a1=relu(z@W1j+b1) -> LDS | B: p_j = a1@W2j (partial pre-act a2) ->
// mailbox -> flag | gap: out/lat/x | poll 3 peer flags | C': sum 4 partials
// +b2, ReLU -> a2 LDS | C: v = a2@W3 (full, redundant per block) | D: h+=0.1v
// (registers, v-layout), rebuild z. Flags sc1 (proven); data sc0 iff probe.

#define TT 1000
#define II 16
#define LL 128
#define HH 512
#define OO 64
#define BB 512

typedef _Float16 f16;
typedef _Float16 f16x8 __attribute__((ext_vector_type(8)));
typedef _Float16 f16x4 __attribute__((ext_vector_type(4)));
typedef float    f32x4 __attribute__((ext_vector_type(4)));
typedef unsigned u32x2 __attribute__((ext_vector_type(2)));
typedef unsigned u32x4 __attribute__((ext_vector_type(4)));

#define MFMA16(a,b,c) __builtin_amdgcn_mfma_f32_16x16x32_f16((a),(b),(c),0,0,0)

// LDS row strides: row byte-size multiple of 128 (XOR swizzle block).
#define ZS   320   // 640B = 5*128 : z 0..159 | a1 160..287
#define W1S  192   // 384B = 3*128 : k 0..159 (144 data + 16 zero)
#define A2SS 512   // 1024B

#define SWB(rowptr,row,colf16) \
  ((void*)((char*)(rowptr) + ((2*(colf16)) ^ (((row)&7)<<4))))

struct Lds {
  f16 w1t[128][W1S];   // W1^T col-slice [n=128][k]
  f16 act[16][ZS];     // z (0..159) | a1 (160..287); z rows 8..15 stay zero
  f16 a2s[16][A2SS];   // full a2 (rows 0..7 valid, 8..15 zeroed once)
  float b2c[512];
  int xtmp[4];
};

// ---- always-coherent (L3) primitives ----
__device__ __forceinline__ void st_sc1_u32(void* p, unsigned v) {
  asm volatile("global_store_dword %0, %1, off sc0 sc1" :: "v"(p), "v"(v) : "memory");
}
__device__ __forceinline__ unsigned ld_sc1_u32(const void* p) {
  unsigned r;
  asm volatile("global_load_dword %0, %1, off sc0 sc1\n\ts_waitcnt vmcnt(0)"
               : "=v"(r) : "v"(p) : "memory");
  return r;
}
// ---- XCD-L2 primitives (probe-gated) ----
__device__ __forceinline__ void st_sc0_u32(void* p, unsigned v) {
  asm volatile("global_store_dword %0, %1, off sc0" :: "v"(p), "v"(v) : "memory");
}
__device__ __forceinline__ unsigned ld_sc0_u32(const void* p) {
  unsigned r;
  asm volatile("global_load_dword %0, %1, off sc0\n\ts_waitcnt vmcnt(0)"
               : "=v"(r) : "v"(p) : "memory");
  return r;
}
template <bool FAST> __device__ __forceinline__ void st_c_u2(void* p, u32x2 v) {
  if constexpr (FAST) asm volatile("global_store_dwordx2 %0, %1, off sc0"     :: "v"(p), "v"(v) : "memory");
  else                asm volatile("global_store_dwordx2 %0, %1, off sc0 sc1" :: "v"(p), "v"(v) : "memory");
}
template <bool FAST> __device__ __forceinline__ u32x4 ld_c_u4(const void* p) {
  u32x4 r;
  if constexpr (FAST) asm volatile("global_load_dwordx4 %0, %1, off sc0"     : "=v"(r) : "v"(p) : "memory");
  else                asm volatile("global_load_dwordx4 %0, %1, off sc0 sc1" : "=v"(r) : "v"(p) : "memory");
  return r;
}
__device__ __forceinline__ void vm_drain() {
  asm volatile("s_waitcnt vmcnt(0)" ::: "memory");
  __builtin_amdgcn_sched_barrier(0);   // rule #18
}

__device__ __forceinline__ f16x8 ldfrag(const float* p, int stride) {
  f16x8 r;
#pragma unroll
  for (int e = 0; e < 8; ++e) r[e] = (f16)p[(size_t)e * stride];
  return r;
}

// flags per group: 64 u32, member m at [m*16]
template <bool FAST>
__device__ __forceinline__ void run_loop(
    Lds& s, const float* __restrict__ x,
    float* __restrict__ out, float* __restrict__ lat,
    unsigned* __restrict__ fl, f16* __restrict__ pbuf,
    const f16x8 (&w2f)[4][8], const f16x8 (&w3f)[16][2], const f16x8 (&wrf)[4],
    float b1v0, float b1v1, float b3v0, float b3v1, f32x4 brv,
    int j, int g, int tid, int w, int lr, int lk) {
  const int lane = tid & 63;
  const int r8 = tid >> 4, cc = tid & 15;           // tid<128: x/z row,col
  const size_t xo = (size_t)(g * 8 + r8) * TT * II + cc;
  float xr = 0.f;
  float hv[8] = {0.f,0.f,0.f,0.f,0.f,0.f,0.f,0.f};  // h[4lk+e][32w+nt*16+lr]

  for (int t = 0; t < TT; ++t) {
    const int par = t & 1;
    f16* const pb = pbuf + (size_t)(g * 2 + par) * (4 * 8 * 512);

    // -------- A: a1 = relu(z @ W1_j + b1) -> act cols 160.. ---------------
    {
      f32x4 acc0 = {0.f,0.f,0.f,0.f}, acc1 = {0.f,0.f,0.f,0.f};
#pragma unroll
      for (int kt = 0; kt < 5; ++kt) {
        f16x8 zf = *(const f16x8*)SWB(&s.act[lr][0], lr, kt * 32 + lk * 8);
        const int n0 = 32 * w + lr, n1 = 32 * w + 16 + lr;
        f16x8 b0 = *(const f16x8*)SWB(&s.w1t[n0][0], n0, kt * 32 + lk * 8);
        acc0 = MFMA16(zf, b0, acc0);
        f16x8 b1f = *(const f16x8*)SWB(&s.w1t[n1][0], n1, kt * 32 + lk * 8);
        acc1 = MFMA16(zf, b1f, acc1);
      }
#pragma unroll
      for (int e = 0; e < 4; ++e) {
        float v0 = acc0[e] + b1v0; v0 = v0 > 0.f ? v0 : 0.f;
        float v1 = acc1[e] + b1v1; v1 = v1 > 0.f ? v1 : 0.f;
        *(f16*)SWB(&s.act[4*lk+e][0], 4*lk+e, 160 + 32*w + lr)      = (f16)v0;
        *(f16*)SWB(&s.act[4*lk+e][0], 4*lk+e, 160 + 32*w + 16 + lr) = (f16)v1;
      }
    }
    __syncthreads();   // a1 ready (cross-wave)

    // -------- B: p_j = a1 @ W2_j (partial pre-act a2), store rows<8 -------
    {
      f16x8 af[4];
#pragma unroll
      for (int kt = 0; kt < 4; ++kt)
        af[kt] = *(const f16x8*)SWB(&s.act[lr][0], lr, 160 + kt * 32 + lk * 8);
      f32x4 pacc[8];
#pragma unroll
      for (int nt = 0; nt < 8; ++nt) pacc[nt] = (f32x4){0.f,0.f,0.f,0.f};
#pragma unroll
      for (int kt = 0; kt < 4; ++kt)
#pragma unroll
        for (int nt = 0; nt < 8; ++nt)
          pacc[nt] = MFMA16(w2f[kt][nt], af[kt], pacc[nt]);
      if (lr < 8) {
#pragma unroll
        for (int nt = 0; nt < 8; ++nt) {
          f16x4 o;
#pragma unroll
          for (int e = 0; e < 4; ++e) o[e] = (f16)pacc[nt][e];
          st_c_u2<FAST>(pb + (size_t)j * 4096 + (size_t)lr * 512 +
                        128 * w + nt * 16 + 4 * lk,
                        __builtin_bit_cast(u32x2, o));
        }
      }
    }
    vm_drain();
    __syncthreads();
    if (tid == 0) st_sc1_u32(fl + j * 16, (unsigned)(t + 1));

    // -------- gap: out_{t-1} (w0), lat_{t-1} from hv, x prefetch ----------
    if (t > 0) {
      if (w == 0) {
        f32x4 oc = {0.f,0.f,0.f,0.f};
#pragma unroll
        for (int kt = 0; kt < 4; ++kt) {
          f16x8 zf = *(const f16x8*)SWB(&s.act[lr][0], lr, kt * 32 + lk * 8);
          oc = MFMA16(wrf[kt], zf, oc);
        }
        if (lr < 8) {
          f32x4 ov;
#pragma unroll
          for (int e = 0; e < 4; ++e) ov[e] = oc[e] + brv[e];
          *(f32x4*)&out[((size_t)(g*8+lr)*TT + (t-1))*OO + 16*j + 4*lk] = ov;
        }
      }
      if (lk < 2) {
#pragma unroll
        for (int nt = 0; nt < 2; ++nt)
#pragma unroll
          for (int e = 0; e < 4; ++e)
            lat[((size_t)(g*8 + 4*lk+e)*TT + (t-1))*LL + 32*w + nt*16 + lr] =
                hv[nt*4+e];
      }
    }
    if (tid < 128 && t + 1 < TT) xr = x[xo + (size_t)(t + 1) * II];

    // -------- WAIT: poll 3 peer flags (own data is program-ordered) -------
    if (lane < 4 && lane != j) {
      const unsigned* fp = fl + lane * 16;
      while (ld_sc1_u32(fp) < (unsigned)(t + 1)) { }
    }

    // -------- C': a2 = relu(sum_m p_m + b2) -> a2s ------------------------
    {
#pragma unroll
      for (int it = 0; it < 2; ++it) {
        const int sidx = tid + it * 256;            // 512 slots of 8 f16
        const int row = sidx >> 6, cg = sidx & 63;
        u32x4 q[4];
#pragma unroll
        for (int m = 0; m < 4; ++m)
          q[m] = ld_c_u4<FAST>(pb + (size_t)m * 4096 + (size_t)sidx * 8);
        vm_drain();
        float sm[8] = {0.f,0.f,0.f,0.f,0.f,0.f,0.f,0.f};
#pragma unroll
        for (int m = 0; m < 4; ++m) {
          f16x8 ph = __builtin_bit_cast(f16x8, q[m]);
#pragma unroll
          for (int e = 0; e < 8; ++e) sm[e] += (float)ph[e];
        }
        f16x8 a2v;
#pragma unroll
        for (int e = 0; e < 8; ++e) {
          float vv = sm[e] + s.b2c[cg * 8 + e];
          a2v[e] = (f16)(vv > 0.f ? vv : 0.f);
        }
        *(f16x8*)SWB(&s.a2s[row][0], row, cg * 8) = a2v;
      }
    }
    __syncthreads();   // a2 ready

    // -------- C: v = a2 @ W3 (full, redundant) ----------------------------
    f32x4 accv0 = {0.f,0.f,0.f,0.f}, accv1 = {0.f,0.f,0.f,0.f};
#pragma unroll
    for (int kt = 0; kt < 16; ++kt) {
      f16x8 a2f = *(const f16x8*)SWB(&s.a2s[lr][0], lr, kt * 32 + lk * 8);
      accv0 = MFMA16(a2f, w3f[kt][0], accv0);
      accv1 = MFMA16(a2f, w3f[kt][1], accv1);
    }

    // -------- D: h += 0.1(v+b3); rebuild z + x ----------------------------
#pragma unroll
    for (int e = 0; e < 4; ++e) {
      hv[e]     += 0.1f * (accv0[e] + b3v0);
      hv[4 + e] += 0.1f * (accv1[e] + b3v1);
    }
    if (lk < 2) {
#pragma unroll
      for (int nt = 0; nt < 2; ++nt)
#pragma unroll
        for (int e = 0; e < 4; ++e)
          *(f16*)SWB(&s.act[4*lk+e][0], 4*lk+e, 32*w + nt*16 + lr) =
              (f16)hv[nt*4+e];
    }
    if (tid < 128)
      *(f16*)SWB(&s.act[r8][0], r8, 128 + cc) = (f16)((t+1 < TT) ? xr : 0.f);
    __syncthreads();   // z ready for next A
  }

  // -------- epilogue: out + lat for t = TT-1 ------------------------------
  if (w == 0) {
    f32x4 oc = {0.f,0.f,0.f,0.f};
#pragma unroll
    for (int kt = 0; kt < 4; ++kt) {
      f16x8 zf = *(const f16x8*)SWB(&s.act[lr][0], lr, kt * 32 + lk * 8);
      oc = MFMA16(wrf[kt], zf, oc);
    }
    if (lr < 8) {
      f32x4 ov;
#pragma unroll
      for (int e = 0; e < 4; ++e) ov[e] = oc[e] + brv[e];
      *(f32x4*)&out[((size_t)(g*8+lr)*TT + (TT-1))*OO + 16*j + 4*lk] = ov;
    }
  }
  if (lk < 2) {
#pragma unroll
    for (int nt = 0; nt < 2; ++nt)
#pragma unroll
      for (int e = 0; e < 4; ++e)
        lat[((size_t)(g*8 + 4*lk+e)*TT + (TT-1))*LL + 32*w + nt*16 + lr] =
            hv[nt*4+e];
  }
}

__launch_bounds__(256, 1)
__global__ void node_scan_kernel(
    const float* __restrict__ x,
    const float* __restrict__ W1, const float* __restrict__ b1,
    const float* __restrict__ W2, const float* __restrict__ b2,
    const float* __restrict__ W3, const float* __restrict__ b3,
    const float* __restrict__ Wr, const float* __restrict__ br,
    float* __restrict__ out,
    unsigned* __restrict__ flags, unsigned* __restrict__ xccbuf,
    unsigned* __restrict__ pflag, unsigned* __restrict__ pack,
    unsigned* __restrict__ verd,  unsigned* __restrict__ pdata,
    f16* __restrict__ pbuf)
{
  __shared__ Lds s;
  const int tid  = threadIdx.x;
  const int bid  = blockIdx.x;
  const int q    = bid >> 3;
  const int j    = q & 3;                      // member 0..3
  const int g    = (bid & 7) + 8 * (q >> 2);   // group 0..63 (co-XCD heuristic)
  const int lane = tid & 63;
  const int w    = tid >> 6;
  const int lr   = lane & 15;
  const int lk   = lane >> 4;

  float* lat = out + (size_t)BB * TT * OO;

  // -------- register-resident weight fragments ----------------------------
  f16x8 w2f[4][8];   // W2^T: [kt][nt] lane holds W2[128j+kt*32+lk*8+e][128w+nt*16+lr]
  { const float* base = W2 + ((size_t)(128*j + lk*8)) * HH + 128*w + lr;
#pragma unroll
    for (int kt = 0; kt < 4; ++kt)
#pragma unroll
      for (int nt = 0; nt < 8; ++nt)
        w2f[kt][nt] = ldfrag(base + (size_t)kt*32*HH + nt*16, HH);
  }
  f16x8 w3f[16][2];  // W3: [kt][nt] lane holds W3[kt*32+lk*8+e][32w+nt*16+lr]
  { const float* base = W3 + (size_t)(lk*8) * LL + 32*w + lr;
#pragma unroll
    for (int kt = 0; kt < 16; ++kt)
#pragma unroll
      for (int nt = 0; nt < 2; ++nt)
        w3f[kt][nt] = ldfrag(base + (size_t)kt*32*LL + nt*16, LL);
  }
  f16x8 wrf[4];      // Wr^T: lane holds Wr[kt*32+lk*8+e][16j+lr]
  { const float* base = Wr + (size_t)(lk*8) * OO + 16*j + lr;
#pragma unroll
    for (int kt = 0; kt < 4; ++kt)
      wrf[kt] = ldfrag(base + (size_t)kt*32*OO, OO);
  }
  const float b1v0 = b1[128*j + 32*w + lr];
  const float b1v1 = b1[128*j + 32*w + 16 + lr];
  const float b3v0 = b3[32*w + lr];
  const float b3v1 = b3[32*w + 16 + lr];
  f32x4 brv;
#pragma unroll
  for (int e = 0; e < 4; ++e) brv[e] = br[16*j + 4*lk + e];

  // -------- LDS fills ------------------------------------------------------
  { int n = tid & 127, h = tid >> 7;     // 2 threads per n-row
    for (int k = h; k < 144; k += 2)
      *(f16*)SWB(&s.w1t[n][0], n, k) = (f16)W1[(size_t)k * HH + 128*j + n];
    for (int k = 144 + h; k < 160; k += 2)
      *(f16*)SWB(&s.w1t[n][0], n, k) = (f16)0.f;
  }
  for (int i = tid; i < 512; i += 256) s.b2c[i] = b2[i];
  for (int i = tid; i < 16 * ZS; i += 256) ((f16*)s.act)[i] = (f16)0.f;
  for (int i = tid; i < 8 * A2SS; i += 256) ((f16*)&s.a2s[8][0])[i] = (f16)0.f;

  // -------- XCD-placement exchange (sc1, proven live) ----------------------
  int xcc;
  asm volatile("s_getreg_b32 %0, hwreg(HW_REG_XCC_ID)" : "=s"(xcc));
  xcc &= 15;
  if (tid == 0) { st_sc1_u32(xccbuf + g*4 + j, 0x100u | (unsigned)xcc); vm_drain(); }
  if (tid < 4) {
    unsigned v;
    const unsigned* p = xccbuf + g*4 + tid;
    do { v = ld_sc1_u32(p); } while (!(v & 0x100u));
    s.xtmp[tid] = (int)(v & 0xffu);
  }
  __syncthreads();
  bool fast = true;
  for (int k2 = 1; k2 < 4; ++k2) fast = fast && (s.xtmp[k2] == s.xtmp[0]);

  // -------- sc0 coherence probe (3 rounds, no sc0 spin) --------------------
  unsigned okbit = 1u;
  if (fast) {
    unsigned* pd = pdata + g*4;
    unsigned* pf = pflag + g*4;
    unsigned* pa = pack  + g*4;
    const unsigned X = 0x51A00000u | ((unsigned)j << 4);
#pragma unroll 1
    for (int rnd = 0; rnd < 3; ++rnd) {
      unsigned val = (rnd == 1) ? (X | 1u) : X;   // rnd2 restores X
      if (tid == 0) {
        st_sc0_u32(pd + j, val);
        vm_drain();
        st_sc1_u32(pf + j, (unsigned)(rnd + 1));
        vm_drain();
      }
      if (tid < 4) {
        while (ld_sc1_u32(pf + tid) < (unsigned)(rnd + 1)) { }
        if (rnd < 2) {
          unsigned exp = 0x51A00000u | ((unsigned)tid << 4) | (rnd == 1 ? 1u : 0u);
          if (ld_sc0_u32(pd + tid) != exp) okbit = 0u;
        }
      }
      __syncthreads();
      if (tid == 0) { st_sc1_u32(pa + j, (unsigned)(rnd + 1)); vm_drain(); }
      if (tid < 4) { while (ld_sc1_u32(pa + tid) < (unsigned)(rnd + 1)) { } }
      __syncthreads();
    }
    if (tid < 4) s.xtmp[tid] = (int)okbit;
    __syncthreads();
    for (int k2 = 0; k2 < 4; ++k2) fast = fast && (s.xtmp[k2] != 0);
  }
  // -------- verdict exchange ----------------------------------------------
  if (tid == 0) { st_sc1_u32(verd + g*4 + j, 0x100u | (fast ? 1u : 0u)); vm_drain(); }
  if (tid < 4) {
    unsigned v;
    const unsigned* p = verd + g*4 + tid;
    do { v = ld_sc1_u32(p); } while (!(v & 0x100u));
    s.xtmp[tid] = (int)(v & 1u);
  }
  __syncthreads();
  bool FASTRUN = true;
  for (int k2 = 0; k2 < 4; ++k2) FASTRUN = FASTRUN && (s.xtmp[k2] != 0);

  // z_0 = [0 | x_0 | 0]  (rows 0..7 only; rows 8..15 stay zero)
  if (tid < 128) {
    const int rr = tid >> 4, cc = tid & 15;
    *(f16*)SWB(&s.act[rr][0], rr, 128 + cc) =
        (f16)x[(size_t)(g*8 + rr) * TT * II + cc];
  }
  __syncthreads();

  unsigned* const fl = flags + g * 64;
  if (FASTRUN)
    run_loop<true >(s, x, out, lat, fl, pbuf, w2f, w3f, wrf,
                    b1v0, b1v1, b3v0, b3v1, brv, j, g, tid, w, lr, lk);
  else
    run_loop<false>(s, x, out, lat, fl, pbuf, w2f, w3f, wrf,
                    b1v0, b1v1, b3v0, b3v1, brv, j, g, tid, w, lr, lk);
}

extern "C" void kernel_launch(void* const* d_in, const int* in_sizes, int n_in,
                              void* d_out, int out_size, void* d_ws, size_t ws_size,
                              hipStream_t stream) {
  const float* x  = (const float*)d_in[0];
  const float* W1 = (const float*)d_in[1];
  const float* b1 = (const float*)d_in[2];
  const float* W2 = (const float*)d_in[3];
  const float* b2 = (const float*)d_in[4];
  const float* W3 = (const float*)d_in[5];
  const float* b3 = (const float*)d_in[6];
  const float* Wr = (const float*)d_in[7];
  const float* br = (const float*)d_in[8];
  float* out = (float*)d_out;

  // ws: [0,16K) flags (64 groups x 64 u32) | [16K) xcc | [18K) pflag |
  // [20K) pack | [22K) verd  (memset [0,24K)) | [24K,26K) pdata (sc0 probe,
  // NOT memset; rnd2 restores) | [32K) pbuf 2MB (64g x 2par x 4memb x 8x512 f16)
  unsigned* flags  = (unsigned*)d_ws;
  unsigned* xccbuf = (unsigned*)((char*)d_ws + 16384);
  unsigned* pflag  = (unsigned*)((char*)d_ws + 18432);
  unsigned* pack   = (unsigned*)((char*)d_ws + 20480);
  unsigned* verd   = (unsigned*)((char*)d_ws + 22528);
  unsigned* pdata  = (unsigned*)((char*)d_ws + 24576);
  f16* pbuf = (f16*)((char*)d_ws + 32768);

  hipMemsetAsync(d_ws, 0, 24576, stream);  // flags + probe ctrl (not pdata)
  node_scan_kernel<<<256, 256, 0, stream>>>(x, W1, b1, W2, b2, W3, b3, Wr, br,
                                            out, flags, xccbuf, pflag, pack,
                                            verd, pdata, pbuf);
}

// Round 12
// 3494.004 us; speedup vs baseline: 1.7129x; 1.1300x over previous
//
#include <hip/hip_runtime.h>

// NODE scan R12: ONE sync/step, 64 groups x 4 blocks (group = 8 batch rows).
// Block j: W1 cols 128j.. (LDS), W2 rows 128j.. (REGISTERS), full W3
// (REGISTERS), Wr cols 16j.. (registers). R12 = R11 + drain hygiene:
// x prefetch at top of step (hidden under A+B, retired by B's drain);
// lat/out HBM stores after the poll (acks overlap C' partial loads);
// gap holds only register-only out-MFMA; lat writes deduped (wave w==j);
// C' single-drain + packed-f16 reduction. Flags sc1; data sc0 iff probe.

#define TT 1000
#define II 16
#define LL 128
#define HH 512
#define OO 64
#define BB 512

typedef _Float16 f16;
typedef _Float16 f16x8 __attribute__((ext_vector_type(8)));
typedef _Float16 f16x4 __attribute__((ext_vector_type(4)));
typedef float    f32x4 __attribute__((ext_vector_type(4)));
typedef unsigned u32x2 __attribute__((ext_vector_type(2)));
typedef unsigned u32x4 __attribute__((ext_vector_type(4)));

#define MFMA16(a,b,c) __builtin_amdgcn_mfma_f32_16x16x32_f16((a),(b),(c),0,0,0)

// LDS row strides: row byte-size multiple of 128 (XOR swizzle block).
#define ZS   320   // 640B = 5*128 : z 0..159 | a1 160..287
#define W1S  192   // 384B = 3*128 : k 0..159 (144 data + 16 zero)
#define A2SS 512   // 1024B

#define SWB(rowptr,row,colf16) \
  ((void*)((char*)(rowptr) + ((2*(colf16)) ^ (((row)&7)<<4))))

struct Lds {
  f16 w1t[128][W1S];   // W1^T col-slice [n=128][k]
  f16 act[16][ZS];     // z (0..159) | a1 (160..287); z rows 8..15 stay zero
  f16 a2s[16][A2SS];   // full a2 (rows 0..7 valid, 8..15 zeroed once)
  f16 b2h[512];        // b2 pre-converted to f16 (packed adds in C')
  int xtmp[4];
};

// ---- always-coherent (L3) primitives ----
__device__ __forceinline__ void st_sc1_u32(void* p, unsigned v) {
  asm volatile("global_store_dword %0, %1, off sc0 sc1" :: "v"(p), "v"(v) : "memory");
}
__device__ __forceinline__ unsigned ld_sc1_u32(const void* p) {
  unsigned r;
  asm volatile("global_load_dword %0, %1, off sc0 sc1\n\ts_waitcnt vmcnt(0)"
               : "=v"(r) : "v"(p) : "memory");
  return r;
}
// ---- XCD-L2 primitives (probe-gated) ----
__device__ __forceinline__ void st_sc0_u32(void* p, unsigned v) {
  asm volatile("global_store_dword %0, %1, off sc0" :: "v"(p), "v"(v) : "memory");
}
__device__ __forceinline__ unsigned ld_sc0_u32(const void* p) {
  unsigned r;
  asm volatile("global_load_dword %0, %1, off sc0\n\ts_waitcnt vmcnt(0)"
               : "=v"(r) : "v"(p) : "memory");
  return r;
}
template <bool FAST> __device__ __forceinline__ void st_c_u2(void* p, u32x2 v) {
  if constexpr (FAST) asm volatile("global_store_dwordx2 %0, %1, off sc0"     :: "v"(p), "v"(v) : "memory");
  else                asm volatile("global_store_dwordx2 %0, %1, off sc0 sc1" :: "v"(p), "v"(v) : "memory");
}
template <bool FAST> __device__ __forceinline__ u32x4 ld_c_u4(const void* p) {
  u32x4 r;
  if constexpr (FAST) asm volatile("global_load_dwordx4 %0, %1, off sc0"     : "=v"(r) : "v"(p) : "memory");
  else                asm volatile("global_load_dwordx4 %0, %1, off sc0 sc1" : "=v"(r) : "v"(p) : "memory");
  return r;
}
__device__ __forceinline__ void vm_drain() {
  asm volatile("s_waitcnt vmcnt(0)" ::: "memory");
  __builtin_amdgcn_sched_barrier(0);   // rule #18
}

__device__ __forceinline__ f16x8 ldfrag(const float* p, int stride) {
  f16x8 r;
#pragma unroll
  for (int e = 0; e < 8; ++e) r[e] = (f16)p[(size_t)e * stride];
  return r;
}

// flags per group: 64 u32, member m at [m*16]
template <bool FAST>
__device__ __forceinline__ void run_loop(
    Lds& s, const float* __restrict__ x,
    float* __restrict__ out, float* __restrict__ lat,
    unsigned* __restrict__ fl, f16* __restrict__ pbuf,
    const f16x8 (&w2f)[4][8], const f16x8 (&w3f)[16][2], const f16x8 (&wrf)[4],
    float b1v0, float b1v1, float b3v0, float b3v1, f32x4 brv,
    int j, int g, int tid, int w, int lr, int lk) {
  const int lane = tid & 63;
  const int r8 = tid >> 4, cc = tid & 15;           // tid<128: x/z row,col
  const size_t xo = (size_t)(g * 8 + r8) * TT * II + cc;
  float xr = 0.f;
  float hv[8] = {0.f,0.f,0.f,0.f,0.f,0.f,0.f,0.f};  // h[4lk+e][32w+nt*16+lr]

  for (int t = 0; t < TT; ++t) {
    const int par = t & 1;
    f16* const pb = pbuf + (size_t)(g * 2 + par) * (4 * 8 * 512);

    // -------- x prefetch for t+1: hidden under A+B, retired by B's drain ---
    if (tid < 128 && t + 1 < TT) xr = x[xo + (size_t)(t + 1) * II];

    // -------- A: a1 = relu(z @ W1_j + b1) -> act cols 160.. ---------------
    {
      f32x4 acc0 = {0.f,0.f,0.f,0.f}, acc1 = {0.f,0.f,0.f,0.f};
#pragma unroll
      for (int kt = 0; kt < 5; ++kt) {
        f16x8 zf = *(const f16x8*)SWB(&s.act[lr][0], lr, kt * 32 + lk * 8);
        const int n0 = 32 * w + lr, n1 = 32 * w + 16 + lr;
        f16x8 b0 = *(const f16x8*)SWB(&s.w1t[n0][0], n0, kt * 32 + lk * 8);
        acc0 = MFMA16(zf, b0, acc0);
        f16x8 b1f = *(const f16x8*)SWB(&s.w1t[n1][0], n1, kt * 32 + lk * 8);
        acc1 = MFMA16(zf, b1f, acc1);
      }
#pragma unroll
      for (int e = 0; e < 4; ++e) {
        float v0 = acc0[e] + b1v0; v0 = v0 > 0.f ? v0 : 0.f;
        float v1 = acc1[e] + b1v1; v1 = v1 > 0.f ? v1 : 0.f;
        *(f16*)SWB(&s.act[4*lk+e][0], 4*lk+e, 160 + 32*w + lr)      = (f16)v0;
        *(f16*)SWB(&s.act[4*lk+e][0], 4*lk+e, 160 + 32*w + 16 + lr) = (f16)v1;
      }
    }
    __syncthreads();   // a1 ready (cross-wave)

    // -------- B: p_j = a1 @ W2_j (partial pre-act a2), store rows<8 -------
    {
      f16x8 af[4];
#pragma unroll
      for (int kt = 0; kt < 4; ++kt)
        af[kt] = *(const f16x8*)SWB(&s.act[lr][0], lr, 160 + kt * 32 + lk * 8);
      f32x4 pacc[8];
#pragma unroll
      for (int nt = 0; nt < 8; ++nt) pacc[nt] = (f32x4){0.f,0.f,0.f,0.f};
#pragma unroll
      for (int kt = 0; kt < 4; ++kt)
#pragma unroll
        for (int nt = 0; nt < 8; ++nt)
          pacc[nt] = MFMA16(w2f[kt][nt], af[kt], pacc[nt]);
      if (lr < 8) {
#pragma unroll
        for (int nt = 0; nt < 8; ++nt) {
          f16x4 o;
#pragma unroll
          for (int e = 0; e < 4; ++e) o[e] = (f16)pacc[nt][e];
          st_c_u2<FAST>(pb + (size_t)j * 4096 + (size_t)lr * 512 +
                        128 * w + nt * 16 + 4 * lk,
                        __builtin_bit_cast(u32x2, o));
        }
      }
    }
    vm_drain();        // retires p stores AND the x prefetch (queues clean)
    __syncthreads();
    if (tid == 0) st_sc1_u32(fl + j * 16, (unsigned)(t + 1));

    // -------- gap: register-only out-MFMA for t-1 (w0); no vm ops ---------
    f32x4 oreg = {0.f,0.f,0.f,0.f};
    if (t > 0 && w == 0) {
#pragma unroll
      for (int kt = 0; kt < 4; ++kt) {
        f16x8 zf = *(const f16x8*)SWB(&s.act[lr][0], lr, kt * 32 + lk * 8);
        oreg = MFMA16(wrf[kt], zf, oreg);
      }
    }

    // -------- WAIT: poll 3 peer flags (clean vm queues -> fast detect) ----
    if (lane < 4 && lane != j) {
      const unsigned* fp = fl + lane * 16;
      while (ld_sc1_u32(fp) < (unsigned)(t + 1)) { }
    }

    // -------- deferred HBM stores (acks overlap C' partial loads) ---------
    if (t > 0) {
      if (w == j && lk < 2) {   // dedup: wave j stores its own 32-col slice
#pragma unroll
        for (int nt = 0; nt < 2; ++nt)
#pragma unroll
          for (int e = 0; e < 4; ++e)
            lat[((size_t)(g*8 + 4*lk+e)*TT + (t-1))*LL + 32*w + nt*16 + lr] =
                hv[nt*4+e];
      }
      if (w == 0 && lr < 8) {
        f32x4 ov;
#pragma unroll
        for (int e = 0; e < 4; ++e) ov[e] = oreg[e] + brv[e];
        *(f32x4*)&out[((size_t)(g*8+lr)*TT + (t-1))*OO + 16*j + 4*lk] = ov;
      }
    }

    // -------- C': a2 = relu(sum_m p_m + b2), packed f16 -------------------
    {
      u32x4 q[2][4];
#pragma unroll
      for (int it = 0; it < 2; ++it) {
        const int sidx = tid + it * 256;            // 512 slots of 8 f16
#pragma unroll
        for (int m = 0; m < 4; ++m)
          q[it][m] = ld_c_u4<FAST>(pb + (size_t)m * 4096 + (size_t)sidx * 8);
      }
      vm_drain();   // also retires the lat/out stores above
#pragma unroll
      for (int it = 0; it < 2; ++it) {
        const int sidx = tid + it * 256;
        const int row = sidx >> 6, cg = sidx & 63;
        f16x8 p0 = __builtin_bit_cast(f16x8, q[it][0]);
        f16x8 p1 = __builtin_bit_cast(f16x8, q[it][1]);
        f16x8 p2 = __builtin_bit_cast(f16x8, q[it][2]);
        f16x8 p3 = __builtin_bit_cast(f16x8, q[it][3]);
        f16x8 bv = *(const f16x8*)&s.b2h[cg * 8];
        f16x8 sm = (p0 + p1) + (p2 + p3) + bv;
        f16x8 a2v;
#pragma unroll
        for (int e = 0; e < 8; ++e)
          a2v[e] = sm[e] > (f16)0.f ? sm[e] : (f16)0.f;
        *(f16x8*)SWB(&s.a2s[row][0], row, cg * 8) = a2v;
      }
    }
    __syncthreads();   // a2 ready

    // -------- C: v = a2 @ W3 (full, redundant) ----------------------------
    f32x4 accv0 = {0.f,0.f,0.f,0.f}, accv1 = {0.f,0.f,0.f,0.f};
#pragma unroll
    for (int kt = 0; kt < 16; ++kt) {
      f16x8 a2f = *(const f16x8*)SWB(&s.a2s[lr][0], lr, kt * 32 + lk * 8);
      accv0 = MFMA16(a2f, w3f[kt][0], accv0);
      accv1 = MFMA16(a2f, w3f[kt][1], accv1);
    }

    // -------- D: h += 0.1(v+b3); rebuild z + x ----------------------------
#pragma unroll
    for (int e = 0; e < 4; ++e) {
      hv[e]     += 0.1f * (accv0[e] + b3v0);
      hv[4 + e] += 0.1f * (accv1[e] + b3v1);
    }
    if (lk < 2) {
#pragma unroll
      for (int nt = 0; nt < 2; ++nt)
#pragma unroll
        for (int e = 0; e < 4; ++e)
          *(f16*)SWB(&s.act[4*lk+e][0], 4*lk+e, 32*w + nt*16 + lr) =
              (f16)hv[nt*4+e];
    }
    if (tid < 128)
      *(f16*)SWB(&s.act[r8][0], r8, 128 + cc) = (f16)((t+1 < TT) ? xr : 0.f);
    __syncthreads();   // z ready for next A
  }

  // -------- epilogue: out + lat for t = TT-1 ------------------------------
  if (w == 0) {
    f32x4 oc = {0.f,0.f,0.f,0.f};
#pragma unroll
    for (int kt = 0; kt < 4; ++kt) {
      f16x8 zf = *(const f16x8*)SWB(&s.act[lr][0], lr, kt * 32 + lk * 8);
      oc = MFMA16(wrf[kt], zf, oc);
    }
    if (lr < 8) {
      f32x4 ov;
#pragma unroll
      for (int e = 0; e < 4; ++e) ov[e] = oc[e] + brv[e];
      *(f32x4*)&out[((size_t)(g*8+lr)*TT + (TT-1))*OO + 16*j + 4*lk] = ov;
    }
  }
  if (w == j && lk < 2) {
#pragma unroll
    for (int nt = 0; nt < 2; ++nt)
#pragma unroll
      for (int e = 0; e < 4; ++e)
        lat[((size_t)(g*8 + 4*lk+e)*TT + (TT-1))*LL + 32*w + nt*16 + lr] =
            hv[nt*4+e];
  }
}

__launch_bounds__(256, 1)
__global__ void node_scan_kernel(
    const float* __restrict__ x,
    const float* __restrict__ W1, const float* __restrict__ b1,
    const float* __restrict__ W2, const float* __restrict__ b2,
    const float* __restrict__ W3, const float* __restrict__ b3,
    const float* __restrict__ Wr, const float* __restrict__ br,
    float* __restrict__ out,
    unsigned* __restrict__ flags, unsigned* __restrict__ xccbuf,
    unsigned* __restrict__ pflag, unsigned* __restrict__ pack,
    unsigned* __restrict__ verd,  unsigned* __restrict__ pdata,
    f16* __restrict__ pbuf)
{
  __shared__ Lds s;
  const int tid  = threadIdx.x;
  const int bid  = blockIdx.x;
  const int q    = bid >> 3;
  const int j    = q & 3;                      // member 0..3
  const int g    = (bid & 7) + 8 * (q >> 2);   // group 0..63 (co-XCD heuristic)
  const int lane = tid & 63;
  const int w    = tid >> 6;
  const int lr   = lane & 15;
  const int lk   = lane >> 4;

  float* lat = out + (size_t)BB * TT * OO;

  // -------- register-resident weight fragments ----------------------------
  f16x8 w2f[4][8];   // W2^T: lane holds W2[128j+kt*32+lk*8+e][128w+nt*16+lr]
  { const float* base = W2 + ((size_t)(128*j + lk*8)) * HH + 128*w + lr;
#pragma unroll
    for (int kt = 0; kt < 4; ++kt)
#pragma unroll
      for (int nt = 0; nt < 8; ++nt)
        w2f[kt][nt] = ldfrag(base + (size_t)kt*32*HH + nt*16, HH);
  }
  f16x8 w3f[16][2];  // W3: lane holds W3[kt*32+lk*8+e][32w+nt*16+lr]
  { const float* base = W3 + (size_t)(lk*8) * LL + 32*w + lr;
#pragma unroll
    for (int kt = 0; kt < 16; ++kt)
#pragma unroll
      for (int nt = 0; nt < 2; ++nt)
        w3f[kt][nt] = ldfrag(base + (size_t)kt*32*LL + nt*16, LL);
  }
  f16x8 wrf[4];      // Wr^T: lane holds Wr[kt*32+lk*8+e][16j+lr]
  { const float* base = Wr + (size_t)(lk*8) * OO + 16*j + lr;
#pragma unroll
    for (int kt = 0; kt < 4; ++kt)
      wrf[kt] = ldfrag(base + (size_t)kt*32*OO, OO);
  }
  const float b1v0 = b1[128*j + 32*w + lr];
  const float b1v1 = b1[128*j + 32*w + 16 + lr];
  const float b3v0 = b3[32*w + lr];
  const float b3v1 = b3[32*w + 16 + lr];
  f32x4 brv;
#pragma unroll
  for (int e = 0; e < 4; ++e) brv[e] = br[16*j + 4*lk + e];

  // -------- LDS fills ------------------------------------------------------
  { int n = tid & 127, h = tid >> 7;     // 2 threads per n-row
    for (int k = h; k < 144; k += 2)
      *(f16*)SWB(&s.w1t[n][0], n, k) = (f16)W1[(size_t)k * HH + 128*j + n];
    for (int k = 144 + h; k < 160; k += 2)
      *(f16*)SWB(&s.w1t[n][0], n, k) = (f16)0.f;
  }
  for (int i = tid; i < 512; i += 256) s.b2h[i] = (f16)b2[i];
  for (int i = tid; i < 16 * ZS; i += 256) ((f16*)s.act)[i] = (f16)0.f;
  for (int i = tid; i < 8 * A2SS; i += 256) ((f16*)&s.a2s[8][0])[i] = (f16)0.f;

  // -------- XCD-placement exchange (sc1, proven live) ----------------------
  int xcc;
  asm volatile("s_getreg_b32 %0, hwreg(HW_REG_XCC_ID)" : "=s"(xcc));
  xcc &= 15;
  if (tid == 0) { st_sc1_u32(xccbuf + g*4 + j, 0x100u | (unsigned)xcc); vm_drain(); }
  if (tid < 4) {
    unsigned v;
    const unsigned* p = xccbuf + g*4 + tid;
    do { v = ld_sc1_u32(p); } while (!(v & 0x100u));
    s.xtmp[tid] = (int)(v & 0xffu);
  }
  __syncthreads();
  bool fast = true;
  for (int k2 = 1; k2 < 4; ++k2) fast = fast && (s.xtmp[k2] == s.xtmp[0]);

  // -------- sc0 coherence probe (3 rounds, no sc0 spin) --------------------
  unsigned okbit = 1u;
  if (fast) {
    unsigned* pd = pdata + g*4;
    unsigned* pf = pflag + g*4;
    unsigned* pa = pack  + g*4;
    const unsigned X = 0x51A00000u | ((unsigned)j << 4);
#pragma unroll 1
    for (int rnd = 0; rnd < 3; ++rnd) {
      unsigned val = (rnd == 1) ? (X | 1u) : X;   // rnd2 restores X
      if (tid == 0) {
        st_sc0_u32(pd + j, val);
        vm_drain();
        st_sc1_u32(pf + j, (unsigned)(rnd + 1));
        vm_drain();
      }
      if (tid < 4) {
        while (ld_sc1_u32(pf + tid) < (unsigned)(rnd + 1)) { }
        if (rnd < 2) {
          unsigned exp = 0x51A00000u | ((unsigned)tid << 4) | (rnd == 1 ? 1u : 0u);
          if (ld_sc0_u32(pd + tid) != exp) okbit = 0u;
        }
      }
      __syncthreads();
      if (tid == 0) { st_sc1_u32(pa + j, (unsigned)(rnd + 1)); vm_drain(); }
      if (tid < 4) { while (ld_sc1_u32(pa + tid) < (unsigned)(rnd + 1)) { } }
      __syncthreads();
    }
    if (tid < 4) s.xtmp[tid] = (int)okbit;
    __syncthreads();
    for (int k2 = 0; k2 < 4; ++k2) fast = fast && (s.xtmp[k2] != 0);
  }
  // -------- verdict exchange ----------------------------------------------
  if (tid == 0) { st_sc1_u32(verd + g*4 + j, 0x100u | (fast ? 1u : 0u)); vm_drain(); }
  if (tid < 4) {
    unsigned v;
    const unsigned* p = verd + g*4 + tid;
    do { v = ld_sc1_u32(p); } while (!(v & 0x100u));
    s.xtmp[tid] = (int)(v & 1u);
  }
  __syncthreads();
  bool FASTRUN = true;
  for (int k2 = 0; k2 < 4; ++k2) FASTRUN = FASTRUN && (s.xtmp[k2] != 0);

  // z_0 = [0 | x_0 | 0]  (rows 0..7 only; rows 8..15 stay zero)
  if (tid < 128) {
    const int rr = tid >> 4, cc = tid & 15;
    *(f16*)SWB(&s.act[rr][0], rr, 128 + cc) =
        (f16)x[(size_t)(g*8 + rr) * TT * II + cc];
  }
  __syncthreads();

  unsigned* const fl = flags + g * 64;
  if (FASTRUN)
    run_loop<true >(s, x, out, lat, fl, pbuf, w2f, w3f, wrf,
                    b1v0, b1v1, b3v0, b3v1, brv, j, g, tid, w, lr, lk);
  else
    run_loop<false>(s, x, out, lat, fl, pbuf, w2f, w3f, wrf,
                    b1v0, b1v1, b3v0, b3v1, brv, j, g, tid, w, lr, lk);
}

extern "C" void kernel_launch(void* const* d_in, const int* in_sizes, int n_in,
                              void* d_out, int out_size, void* d_ws, size_t ws_size,
                              hipStream_t stream) {
  const float* x  = (const float*)d_in[0];
  const float* W1 = (const float*)d_in[1];
  const float* b1 = (const float*)d_in[2];
  const float* W2 = (const float*)d_in[3];
  const float* b2 = (const float*)d_in[4];
  const float* W3 = (const float*)d_in[5];
  const float* b3 = (const float*)d_in[6];
  const float* Wr = (const float*)d_in[7];
  const float* br = (const float*)d_in[8];
  float* out = (float*)d_out;

  // ws: [0,16K) flags (64 groups x 64 u32) | [16K) xcc | [18K) pflag |
  // [20K) pack | [22K) verd  (memset [0,24K)) | [24K,26K) pdata (sc0 probe,
  // NOT memset; rnd2 restores) | [32K) pbuf 2MB (64g x 2par x 4memb x 8x512)
  unsigned* flags  = (unsigned*)d_ws;
  unsigned* xccbuf = (unsigned*)((char*)d_ws + 16384);
  unsigned* pflag  = (unsigned*)((char*)d_ws + 18432);
  unsigned* pack   = (unsigned*)((char*)d_ws + 20480);
  unsigned* verd   = (unsigned*)((char*)d_ws + 22528);
  unsigned* pdata  = (unsigned*)((char*)d_ws + 24576);
  f16* pbuf = (f16*)((char*)d_ws + 32768);

  hipMemsetAsync(d_ws, 0, 24576, stream);  // flags + probe ctrl (not pdata)
  node_scan_kernel<<<256, 256, 0, stream>>>(x, W1, b1, W2, b2, W3, b3, Wr, br,
                                            out, flags, xccbuf, pflag, pack,
                                            verd, pdata, pbuf);
}